// Round 12
// baseline (467.063 us; speedup 1.0000x reference)
//
#include <hip/hip_runtime.h>
#include <hip/hip_bf16.h>
#include <math.h>

#define NN 8192      // nodes
#define NK 64        // clusters
#define EPSF 1e-6f
// Two-pass E: stream_e (pure streaming: rowsum/colsum/bf16-encode, 2 halves)
// + within_e (MFMA GEMM on L3-hot bf16 copy). ws usage ~82 MB (ws is ~1 GiB).

typedef __attribute__((ext_vector_type(8))) short s16x8;
typedef __attribute__((ext_vector_type(4))) short s16x4;
typedef __attribute__((ext_vector_type(4))) float f32x4;

static __device__ __forceinline__ short f2bf(float x) {
    union { float f; unsigned u; } v; v.f = x;
    unsigned r = (v.u + 0x7fffu + ((v.u >> 16) & 1u)) >> 16;
    return (short)r;
}

static __device__ __forceinline__ void glds16(const void* g, void* s) {
    __builtin_amdgcn_global_load_lds(
        (const __attribute__((address_space(1))) unsigned*)g,
        (__attribute__((address_space(3))) unsigned*)s, 16, 0, 0);
}

// ---------- pre-kernel: A -> ATF fragment-major bf16 + fused argmax/counts/sums ----------
// ATF byte layout: chunk*4096 + nf*1024 + l*16 + 2e  =  bf16(A[chunk*32 + 8*(l>>4) + e][16*nf + (l&15)])
__global__ __launch_bounds__(256) void cvt_at(const float* __restrict__ A,
                                              const float* __restrict__ pos,
                                              unsigned short* __restrict__ ATF,
                                              int* __restrict__ ids,
                                              float* __restrict__ counts,
                                              float* __restrict__ sums) {
    __shared__ unsigned short T[64][72];
    int tid = threadIdx.x;
    int n0 = blockIdx.x * 64;
    int node = tid >> 2;
    int g = tid & 3;
    int k4 = g << 4;
    const float* ap = A + (size_t)(n0 + node) * NK + k4;
    f32x4 x0 = *(const f32x4*)(ap);
    f32x4 x1 = *(const f32x4*)(ap + 4);
    f32x4 x2 = *(const f32x4*)(ap + 8);
    f32x4 x3 = *(const f32x4*)(ap + 12);
#pragma unroll
    for (int e = 0; e < 4; ++e) {
        T[k4 + e][node]      = (unsigned short)f2bf(x0[e]);
        T[k4 + 4 + e][node]  = (unsigned short)f2bf(x1[e]);
        T[k4 + 8 + e][node]  = (unsigned short)f2bf(x2[e]);
        T[k4 + 12 + e][node] = (unsigned short)f2bf(x3[e]);
    }
    {
        float mv = x0[0]; int mi = k4;
#pragma unroll
        for (int e = 0; e < 4; ++e) {
            if (x0[e] > mv) { mv = x0[e]; mi = k4 + e; }
            if (x1[e] > mv) { mv = x1[e]; mi = k4 + 4 + e; }
            if (x2[e] > mv) { mv = x2[e]; mi = k4 + 8 + e; }
            if (x3[e] > mv) { mv = x3[e]; mi = k4 + 12 + e; }
        }
#pragma unroll
        for (int m = 1; m < 4; m <<= 1) {
            float ov = __shfl_xor(mv, m);
            int oi = __shfl_xor(mi, m);
            if (ov > mv || (ov == mv && oi < mi)) { mv = ov; mi = oi; }
        }
        if (g == 0) {
            ids[n0 + node] = mi;
            atomicAdd(&counts[mi], 1.0f);
            atomicAdd(&sums[mi * 2 + 0], pos[(size_t)(n0 + node) * 2 + 0]);
            atomicAdd(&sums[mi * 2 + 1], pos[(size_t)(n0 + node) * 2 + 1]);
        }
    }
    __syncthreads();
#pragma unroll
    for (int pass = 0; pass < 2; ++pass) {
        int oi = pass * 256 + tid;
        int l = oi & 63, nf = (oi >> 6) & 3, cl = oi >> 8;
        int k = (l & 15) + 16 * nf;
        int nb = cl * 32 + (l >> 4) * 8;
        s16x8 v;
#pragma unroll
        for (int e = 0; e < 8; ++e) v[e] = (short)T[k][nb + e];
        size_t chunk = (size_t)blockIdx.x * 2 + cl;
        *(s16x8*)(ATF + ((chunk * 4 + nf) * 64 + l) * 8) = v;
    }
}

// ---------- P1: pure streaming pass over an E half ----------
__global__ __launch_bounds__(256) void stream_e(
    const float* __restrict__ E, int halfrow,
    char* __restrict__ S, float* __restrict__ rowsum,
    float* __restrict__ colpart)
{
    __shared__ float cs[NN];   // 32KB block colsum
    int tid = threadIdx.x;
    int w = tid >> 6, l = tid & 63;
    int bid = blockIdx.x;
    for (int i = tid; i < NN; i += 256) cs[i] = 0.f;
    __syncthreads();

    int rloc0 = bid * 16 + 4 * w;            // half-local first row of wave
    int rowg0 = halfrow + rloc0;             // global
    const float* ebase = E + (size_t)rowg0 * NN + 4 * l;

    float racc = 0.f;
    f32x4 ld[8];
#pragma unroll
    for (int j = 0; j < 8; ++j)
        ld[j] = __builtin_nontemporal_load((const f32x4*)(ebase + (size_t)j * 256));

    for (int ii = 0; ii < 128; ii += 8) {
        int r = ii >> 5;                      // row-local 0..3 (uniform)
        int rloc = rloc0 + r;
        char* srow = S + (size_t)rloc * 16384;
        unsigned swz = ((unsigned)(rloc & 7)) << 4;
#pragma unroll
        for (int j = 0; j < 8; ++j) {
            f32x4 v = ld[j];
            int ni = ii + 8 + j;
            int nif = (ni < 128) ? ni : 0;
            ld[j] = __builtin_nontemporal_load(
                (const f32x4*)(ebase + (size_t)(nif >> 5) * NN + (size_t)(nif & 31) * 256));
            int c = (ii + j) & 31;
            racc += (v[0] + v[1]) + (v[2] + v[3]);
            int col = c * 256 + 4 * l;
            atomicAdd(&cs[col + 0], v[0]);
            atomicAdd(&cs[col + 1], v[1]);
            atomicAdd(&cs[col + 2], v[2]);
            atomicAdd(&cs[col + 3], v[3]);
            s16x4 b; b[0] = f2bf(v[0]); b[1] = f2bf(v[1]); b[2] = f2bf(v[2]); b[3] = f2bf(v[3]);
            *(s16x4*)(srow + c * 512 + ((8u * (unsigned)l) ^ swz)) = b;
        }
        if ((ii & 31) == 24) {               // row complete
#pragma unroll
            for (int m = 1; m < 64; m <<= 1) racc += __shfl_xor(racc, m);
            if (l == 0) rowsum[rowg0 + r] = racc;
            racc = 0.f;
        }
    }
    __syncthreads();
    for (int i = tid; i < NN; i += 256)
        colpart[(size_t)bid * NN + i] = cs[i];
}

// ---------- P2: within GEMM on bf16 S (L3-hot) ----------
// 512 blocks (32 jw x 16 rg) x 256 thr. 8 tiles of 32 rows x 256-col window.
// Wave: msub=w&1 (16 rows), kh=w>>1 (4 of 8 K-chunks).
__global__ __launch_bounds__(256) void within_e(
    const char* __restrict__ S, const float* __restrict__ A,
    const unsigned short* __restrict__ ATF,
    float* __restrict__ within_part, int halfrow, int partoff)
{
    __shared__ char Ebuf[2][16384];
    __shared__ char ATFl[32768];             // 8 chunks x 4096B
    __shared__ float red[4];

    int tid = threadIdx.x;
    int w = tid >> 6, l = tid & 63;
    int lm = l & 15, lg = l >> 4;
    int jw = blockIdx.x & 31;
    int rg = blockIdx.x >> 5;
    int msub = w & 1, kh = w >> 1;
    int lrow = l >> 5, lcol = (l & 31) * 16;

    // prologue: stage ATF window (32KB = 8 instrs/wave) + tile 0 (16KB)
#pragma unroll
    for (int q = 0; q < 8; ++q) {
        int i = 8 * w + q;                   // 0..31 KB-slots
        glds16((const char*)ATF + (size_t)jw * 32768 + (size_t)i * 1024 + (size_t)l * 16,
               ATFl + i * 1024);
    }
#pragma unroll
    for (int q = 0; q < 4; ++q) {
        int i = 4 * w + q;
        glds16(S + (size_t)(rg * 256 + 2 * i + lrow) * 16384 + jw * 512 + lcol,
               Ebuf[0] + i * 1024);
    }

    float wsum = 0.f;
    for (int t = 0; t < 8; ++t) {
        asm volatile("s_waitcnt vmcnt(0)" ::: "memory");   // stage(t) (+ATF at t=0) landed
        __builtin_amdgcn_s_barrier();
        __builtin_amdgcn_sched_barrier(0);
        const char* buf = Ebuf[t & 1];
        if (t < 7) {
            char* nb = Ebuf[(t + 1) & 1];
#pragma unroll
            for (int q = 0; q < 4; ++q) {
                int i = 4 * w + q;
                glds16(S + (size_t)(rg * 256 + (t + 1) * 32 + 2 * i + lrow) * 16384 + jw * 512 + lcol,
                       nb + i * 1024);
            }
        }
        float a0[4], a1[4], a2[4], a3[4];
#pragma unroll
        for (int rr = 0; rr < 4; ++rr) {
            const float* ar = A + (size_t)(halfrow + rg * 256 + t * 32 + 16 * msub + 4 * lg + rr) * NK + lm;
            a0[rr] = ar[0]; a1[rr] = ar[16]; a2[rr] = ar[32]; a3[rr] = ar[48];
        }
        f32x4 D0 = {0.f,0.f,0.f,0.f}, D1 = D0, D2 = D0, D3 = D0;
#pragma unroll
        for (int k2 = 0; k2 < 4; ++k2) {
            int kc = 4 * kh + k2;
            s16x8 af = *(const s16x8*)(buf + (16 * msub + lm) * 512 +
                        (((unsigned)(kc * 64 + 16 * lg)) ^ (((unsigned)(lm & 7)) << 4)));
            const char* ab = ATFl + kc * 4096 + (size_t)l * 16;
            s16x8 b0 = *(const s16x8*)(ab);
            s16x8 b1 = *(const s16x8*)(ab + 1024);
            s16x8 b2 = *(const s16x8*)(ab + 2048);
            s16x8 b3 = *(const s16x8*)(ab + 3072);
            D0 = __builtin_amdgcn_mfma_f32_16x16x32_bf16(af, b0, D0, 0, 0, 0);
            D1 = __builtin_amdgcn_mfma_f32_16x16x32_bf16(af, b1, D1, 0, 0, 0);
            D2 = __builtin_amdgcn_mfma_f32_16x16x32_bf16(af, b2, D2, 0, 0, 0);
            D3 = __builtin_amdgcn_mfma_f32_16x16x32_bf16(af, b3, D3, 0, 0, 0);
        }
#pragma unroll
        for (int rr = 0; rr < 4; ++rr)
            wsum += D0[rr] * a0[rr] + D1[rr] * a1[rr] + D2[rr] * a2[rr] + D3[rr] * a3[rr];
    }

#pragma unroll
    for (int m = 1; m < 64; m <<= 1) wsum += __shfl_xor(wsum, m);
    if (l == 0) red[w] = wsum;
    __syncthreads();
    if (tid == 0) within_part[partoff + blockIdx.x] = red[0] + red[1] + red[2] + red[3];
}

// ---------- reduce colsum partials ----------
__global__ __launch_bounds__(256) void reduce_cols(const float* __restrict__ part,
                                                   float* __restrict__ colsum) {
    int j = blockIdx.x * 256 + threadIdx.x;
    float s0 = 0.f, s1 = 0.f, s2 = 0.f, s3 = 0.f;
    for (int p = 0; p < 512; p += 4) {
        s0 += part[(size_t)(p + 0) * NN + j];
        s1 += part[(size_t)(p + 1) * NN + j];
        s2 += part[(size_t)(p + 2) * NN + j];
        s3 += part[(size_t)(p + 3) * NN + j];
    }
    colsum[j] = (s0 + s1) + (s2 + s3);
}

// ---------- spatial pass 2: distances to centroids ----------
__global__ __launch_bounds__(256) void spatial2(
    const int* __restrict__ ids, const float* __restrict__ pos,
    const float* __restrict__ counts, const float* __restrict__ sums,
    float* __restrict__ distsum, int* __restrict__ maxid)
{
    __shared__ float ds[64];
    __shared__ int mx;
    int tid = threadIdx.x;
    if (tid < 64) ds[tid] = 0.f;
    if (tid == 0) mx = 0;
    __syncthreads();
    int i = blockIdx.x * 256 + tid;
    int id = ids[i];
    float den = counts[id] + EPSF;
    float cx = sums[id * 2 + 0] / den;
    float cy = sums[id * 2 + 1] / den;
    float dx = pos[(size_t)i * 2 + 0] - cx;
    float dy = pos[(size_t)i * 2 + 1] - cy;
    atomicAdd(&ds[id], sqrtf(dx * dx + dy * dy));
    atomicMax(&mx, id);
    __syncthreads();
    if (tid < 64) atomicAdd(&distsum[tid], ds[tid]);
    if (tid == 0) atomicMax(maxid, mx);
}

// ---------- finalize ----------
__global__ __launch_bounds__(256) void finalize(
    const float* __restrict__ rowsum, const float* __restrict__ colsum,
    const float* __restrict__ cons, const float* __restrict__ gen,
    const float* __restrict__ within_part, const float* __restrict__ counts,
    const float* __restrict__ distsum, const int* __restrict__ maxid,
    float* __restrict__ out)
{
    __shared__ float redb[4], rede[4], redw[4];
    int tid = threadIdx.x;
    int w = tid >> 6, l = tid & 63;
    float bacc = 0.f, eacc = 0.f, wacc = 0.f;
    for (int i = tid; i < NN; i += 256) {
        float imb = (cons[i] - gen[i]) - (colsum[i] - rowsum[i]);
        bacc += imb * imb;
        eacc += rowsum[i];
    }
    for (int i = tid; i < 1024; i += 256) wacc += within_part[i];
#pragma unroll
    for (int m = 1; m < 64; m <<= 1) {
        bacc += __shfl_xor(bacc, m);
        eacc += __shfl_xor(eacc, m);
        wacc += __shfl_xor(wacc, m);
    }
    if (l == 0) { redb[w] = bacc; rede[w] = eacc; redw[w] = wacc; }
    __syncthreads();

    float sacc = 0.f;
    if (tid < 64) {
        float c = counts[tid];
        float avg = distsum[tid] / (c + EPSF);
        sacc = (c >= 2.0f) ? avg : 0.f;
#pragma unroll
        for (int m = 1; m < 64; m <<= 1) sacc += __shfl_xor(sacc, m);
    }
    if (tid == 0) {
        float balance = (redb[0] + redb[1] + redb[2] + redb[3]) / (float)NN;
        float sumE = rede[0] + rede[1] + rede[2] + rede[3];
        float W = redw[0] + redw[1] + redw[2] + redw[3];
        float clustering = (sumE - 2.0f * W) / ((float)NN * (float)NN + EPSF);
        float nc = (float)(maxid[0] + 1) + EPSF;
        float spatial = sacc / nc;
        float total = 1.0f * balance + 0.5f * spatial + 0.3f * clustering;
        out[0] = total;
        out[1] = balance;
        out[2] = spatial;
        out[3] = clustering;
    }
}

extern "C" void kernel_launch(void* const* d_in, const int* in_sizes, int n_in,
                              void* d_out, int out_size, void* d_ws, size_t ws_size,
                              hipStream_t stream) {
    const float* E    = (const float*)d_in[0];
    const float* A    = (const float*)d_in[1];
    const float* pos  = (const float*)d_in[2];
    const float* cons = (const float*)d_in[3];
    const float* gen  = (const float*)d_in[4];
    float* out = (float*)d_out;

    char* ws = (char*)d_ws;
    unsigned short* ATF = (unsigned short*)ws;                     // 1 MB
    char*  S           = ws + (size_t)2 * NK * NN;                 // 64 MB (bf16 half, swizzled)
    float* colpart     = (float*)(S + (size_t)4096 * 16384);       // 512*8192*4 = 16 MB
    float* rowsum      = colpart + (size_t)512 * NN;               // [N]
    float* colsum      = rowsum + NN;                              // [N]
    float* counts      = colsum + NN;                              // [64]  <- zero from here
    float* sums        = counts + 64;                              // [64][2]
    float* distsum     = sums + 128;                               // [64]
    int*   maxid       = (int*)(distsum + 64);                     // [1]   <- zero to here
    float* within_part = (float*)(maxid + 1);                      // [1024]
    int*   ids         = (int*)(within_part + 1024);               // [N]

    size_t zbytes = (64 + 128 + 64 + 1) * 4;
    hipMemsetAsync(counts, 0, zbytes, stream);

    cvt_at  <<<NN / 64, 256, 0, stream>>>(A, pos, ATF, ids, counts, sums);
    stream_e<<<256, 256, 0, stream>>>(E, 0, S, rowsum, colpart);
    within_e<<<512, 256, 0, stream>>>(S, A, ATF, within_part, 0, 0);
    stream_e<<<256, 256, 0, stream>>>(E, 4096, S, rowsum, colpart + (size_t)256 * NN);
    within_e<<<512, 256, 0, stream>>>(S, A, ATF, within_part, 4096, 512);
    reduce_cols<<<NN / 256, 256, 0, stream>>>(colpart, colsum);
    spatial2<<<NN / 256, 256, 0, stream>>>(ids, pos, counts, sums, distsum, maxid);
    finalize<<<1, 256, 0, stream>>>(rowsum, colsum, cons, gen, within_part, counts, distsum, maxid, out);
}